// Round 1
// baseline (859.269 us; speedup 1.0000x reference)
//
#include <hip/hip_runtime.h>
#include <cstdint>
#include <cstddef>

#define BB 32
#define NN 24564
#define CC 81
#define CM1 80
#define KTOP 100
#define MAXDET 100
#define NBINS 8192
#define BSHIFT 13
#define BASEBITS 0x3C000000u
#define CAP 4096

// ---------------- decode boxes: [B,N,4] loc + [N,4] priors -> corner boxes ----------------
__global__ __launch_bounds__(256) void decode_kernel(const float* __restrict__ loc,
                                                     const float* __restrict__ priors,
                                                     float* __restrict__ boxes) {
    int i = blockIdx.x * 256 + threadIdx.x;
    if (i >= BB * NN) return;
    int n = i % NN;
    float4 l = reinterpret_cast<const float4*>(loc)[i];
    float4 p = reinterpret_cast<const float4*>(priors)[n];
    // cx = l.x * 0.1 * pw + px   (mirror op order, no contraction)
    float cx = __fadd_rn(__fmul_rn(__fmul_rn(l.x, 0.1f), p.z), p.x);
    float cy = __fadd_rn(__fmul_rn(__fmul_rn(l.y, 0.1f), p.w), p.y);
    float w  = __fmul_rn(expf(__fmul_rn(l.z, 0.2f)), p.z);
    float h  = __fmul_rn(expf(__fmul_rn(l.w, 0.2f)), p.w);
    float4 o;
    o.x = __fsub_rn(cx, __fmul_rn(w, 0.5f));
    o.y = __fsub_rn(cy, __fmul_rn(h, 0.5f));
    o.z = __fadd_rn(cx, __fmul_rn(w, 0.5f));
    o.w = __fadd_rn(cy, __fmul_rn(h, 0.5f));
    reinterpret_cast<float4*>(boxes)[i] = o;
}

// ---------------- softmax over C=81 + threshold + transpose to [b_local, 80, N] ----------------
__global__ __launch_bounds__(128) void softmax_tr_kernel(const float* __restrict__ conf,
                                                         float* __restrict__ scoresT,
                                                         int b0) {
    const int TILE = 128;
    const int tiles = (NN + TILE - 1) / TILE;
    int bl = blockIdx.x / tiles;       // chunk-local image
    int bimg = b0 + bl;                // global image
    int n0 = (blockIdx.x % tiles) * TILE;
    int cnt = NN - n0; if (cnt > TILE) cnt = TILE;
    __shared__ __align__(16) float tile[TILE * CC];

    const float* src = conf + ((size_t)bimg * NN + n0) * CC;
    int total = cnt * CC;
    int tid = threadIdx.x;
    int tot4 = total >> 2;
    const float4* src4 = reinterpret_cast<const float4*>(src);
    float4* tile4 = reinterpret_cast<float4*>(tile);
    for (int i = tid; i < tot4; i += 128) tile4[i] = src4[i];
    for (int i = (tot4 << 2) + tid; i < total; i += 128) tile[i] = src[i];
    __syncthreads();

    if (tid < cnt) {
        float* row = tile + tid * CC;
        float mx = row[0];
        for (int c2 = 1; c2 < CC; ++c2) mx = fmaxf(mx, row[c2]);
        float s = 0.f;
        for (int c2 = 0; c2 < CC; ++c2) {
            float e = expf(__fsub_rn(row[c2], mx));
            if (c2 > 0) row[c2] = e;   // cache exp for the divide pass
            s = __fadd_rn(s, e);
        }
        for (int c2 = 1; c2 < CC; ++c2) {
            float sc = __fdiv_rn(row[c2], s);
            row[c2] = (sc > 0.01f) ? sc : 0.f;   // CONF_THRESH fold
        }
    }
    __syncthreads();
    for (int c2 = 1; c2 < CC; ++c2) {
        float* dst = scoresT + ((size_t)bl * CM1 + (c2 - 1)) * NN + n0;
        for (int p = tid; p < cnt; p += 128) dst[p] = tile[p * CC + c2];
    }
}

// ---------------- per-(image,class): exact top-100 (value desc, idx asc) + greedy NMS ----------------
__global__ __launch_bounds__(256) void topk_nms_kernel(const float* __restrict__ scoresT,
                                                       const float* __restrict__ boxes,
                                                       float* __restrict__ nms_scores,
                                                       float* __restrict__ nms_boxes,
                                                       int b0) {
    int bl = blockIdx.x / CM1;
    int c  = blockIdx.x % CM1;
    int bimg = b0 + bl;
    const float* row = scoresT + ((size_t)bl * CM1 + c) * NN;

    __shared__ unsigned int hist[NBINS];          // 32 KB, later aliased as u64 cand[CAP]
    __shared__ unsigned int chunkAgg[256];
    __shared__ int s_total, s_candcnt;
    __shared__ unsigned int s_cut;
    __shared__ float bx[KTOP][4];
    __shared__ float sv[KTOP];
    __shared__ unsigned long long mlo[KTOP], mhi[KTOP];
    __shared__ unsigned long long keeplo, keephi;

    int tid = threadIdx.x;
    for (int i = tid; i < NBINS; i += 256) hist[i] = 0u;
    if (tid == 0) { s_total = 0; s_candcnt = 0; s_cut = 0xFFFFFFFFu; }
    __syncthreads();

    // pass 1: histogram of float bits (scores already thresholded; zeros excluded)
    int cntloc = 0;
    for (int n = tid; n < NN; n += 256) {
        float s = row[n];
        if (s > 0.f) {
            unsigned int bits = __float_as_uint(s);
            unsigned int bin = (bits - BASEBITS) >> BSHIFT;
            if (bin >= NBINS) bin = NBINS - 1;
            atomicAdd(&hist[bin], 1u);
            ++cntloc;
        }
    }
    atomicAdd(&s_total, cntloc);
    __syncthreads();
    int total = s_total;
    int Kt = total < KTOP ? total : KTOP;

    // descending chunk sums + scan to find the cut bin containing rank Kt
    const int CH = NBINS / 256;
    unsigned int mySum = 0;
    int hibin = NBINS - 1 - tid * CH;
    for (int t = 0; t < CH; ++t) mySum += hist[hibin - t];
    chunkAgg[tid] = mySum;
    __syncthreads();
    for (int off = 1; off < 256; off <<= 1) {
        unsigned int add = (tid >= off) ? chunkAgg[tid - off] : 0u;
        __syncthreads();
        chunkAgg[tid] += add;
        __syncthreads();
    }
    unsigned int incl = chunkAgg[tid];
    unsigned int excl = incl - mySum;
    if (Kt > 0 && excl < (unsigned)Kt && (unsigned)Kt <= incl) {
        unsigned int cum = excl;
        int bb = hibin;
        for (int t = 0; t < CH; ++t) {
            int bin = hibin - t;
            cum += hist[bin];
            if (cum >= (unsigned)Kt) { bb = bin; break; }
        }
        unsigned int cutbin = (cum <= CAP) ? (unsigned)bb : (unsigned)(bb + 1);
        s_cut = BASEBITS + (cutbin << BSHIFT);
    }
    __syncthreads();
    unsigned int cut = s_cut;
    __syncthreads();   // hist reads done; safe to alias

    // pass 2: collect candidates (bits >= cut), packed key = (~bits)<<32 | idx
    unsigned long long* cand = reinterpret_cast<unsigned long long*>(hist);
    for (int n = tid; n < NN; n += 256) {
        float s = row[n];
        if (s > 0.f) {
            unsigned int bits = __float_as_uint(s);
            if (bits >= cut) {
                int p = atomicAdd(&s_candcnt, 1);
                if (p < CAP) cand[p] = (((unsigned long long)(~bits)) << 32) | (unsigned int)n;
            }
        }
    }
    __syncthreads();
    int cc = s_candcnt; if (cc > CAP) cc = CAP;
    int S = 1; while (S < cc) S <<= 1; if (S < 2) S = 2;
    for (int i = cc + tid; i < S; i += 256) cand[i] = ~0ull;
    __syncthreads();

    // bitonic ascending sort (smaller key = larger score; ties -> smaller idx)
    for (int k = 2; k <= S; k <<= 1) {
        for (int j = k >> 1; j > 0; j >>= 1) {
            for (int i = tid; i < S; i += 256) {
                int ixj = i ^ j;
                if (ixj > i) {
                    unsigned long long a = cand[i], b2 = cand[ixj];
                    bool up = ((i & k) == 0);
                    if ((a > b2) == up) { cand[i] = b2; cand[ixj] = a; }
                }
            }
            __syncthreads();
        }
    }

    // extract top-100, gather boxes
    if (tid < KTOP) {
        float val = 0.f; unsigned int n = 0;
        if (tid < cc) {
            unsigned long long kk = cand[tid];
            val = __uint_as_float(~(unsigned int)(kk >> 32));
            n = (unsigned int)(kk & 0xFFFFFFFFu);
        }
        sv[tid] = val;
        float4 b4 = reinterpret_cast<const float4*>(boxes)[(size_t)bimg * NN + n];
        bx[tid][0] = b4.x; bx[tid][1] = b4.y; bx[tid][2] = b4.z; bx[tid][3] = b4.w;
    }
    __syncthreads();

    // pairwise IoU masks (exact reference op order)
    if (tid < KTOP) {
        float x1 = bx[tid][0], y1 = bx[tid][1], x2 = bx[tid][2], y2 = bx[tid][3];
        float ai = __fmul_rn(fmaxf(__fsub_rn(x2, x1), 0.f), fmaxf(__fsub_rn(y2, y1), 0.f));
        unsigned long long lo = 0, hi = 0;
        for (int j = 0; j < KTOP; ++j) {
            float jx1 = bx[j][0], jy1 = bx[j][1], jx2 = bx[j][2], jy2 = bx[j][3];
            float iw = fmaxf(__fsub_rn(fminf(x2, jx2), fmaxf(x1, jx1)), 0.f);
            float ih = fmaxf(__fsub_rn(fminf(y2, jy2), fmaxf(y1, jy1)), 0.f);
            float inter = __fmul_rn(iw, ih);
            float aj = __fmul_rn(fmaxf(__fsub_rn(jx2, jx1), 0.f), fmaxf(__fsub_rn(jy2, jy1), 0.f));
            float denom = __fadd_rn(__fsub_rn(__fadd_rn(ai, aj), inter), 1e-8f);
            float iou = __fdiv_rn(inter, denom);
            if (iou > 0.45f) { if (j < 64) lo |= (1ull << j); else hi |= (1ull << (j - 64)); }
        }
        mlo[tid] = lo; mhi[tid] = hi;
    }
    __syncthreads();

    // serial greedy resolve (matches fori_loop exactly)
    if (tid == 0) {
        unsigned long long klo = 0, khi = 0;
        for (int i = 0; i < KTOP; ++i) {
            unsigned long long sup = (mlo[i] & klo) | (mhi[i] & khi);
            bool kp = (sv[i] > 0.f) && (sup == 0ull);
            if (kp) { if (i < 64) klo |= (1ull << i); else khi |= (1ull << (i - 64)); }
        }
        keeplo = klo; keephi = khi;
    }
    __syncthreads();

    if (tid < KTOP) {
        bool kp = (tid < 64) ? ((keeplo >> tid) & 1ull) : ((keephi >> (tid - 64)) & 1ull);
        size_t obase = ((size_t)bimg * CM1 + c) * KTOP + tid;
        nms_scores[obase] = kp ? sv[tid] : 0.f;
        float4 o; o.x = bx[tid][0]; o.y = bx[tid][1]; o.z = bx[tid][2]; o.w = bx[tid][3];
        reinterpret_cast<float4*>(nms_boxes)[obase] = o;
    }
}

// ---------------- per-image final top-100 over 8000 candidates ----------------
__global__ __launch_bounds__(256) void final_topk_kernel(const float* __restrict__ nms_scores,
                                                         const float* __restrict__ nms_boxes,
                                                         float* __restrict__ out) {
    int b = blockIdx.x;
    __shared__ unsigned long long arr[8192];   // 64 KB
    int tid = threadIdx.x;
    const int NCAND = CM1 * KTOP;              // 8000
    const float* srow = nms_scores + (size_t)b * NCAND;
    for (int i = tid; i < 8192; i += 256) {
        unsigned long long key;
        if (i < NCAND) {
            float s = srow[i];
            unsigned int bits = (s > 0.f) ? __float_as_uint(s) : 0u;
            key = (((unsigned long long)(~bits)) << 32) | (unsigned int)i;
        } else key = ~0ull;
        arr[i] = key;
    }
    __syncthreads();
    for (int k = 2; k <= 8192; k <<= 1) {
        for (int j = k >> 1; j > 0; j >>= 1) {
            for (int i = tid; i < 8192; i += 256) {
                int ixj = i ^ j;
                if (ixj > i) {
                    unsigned long long a = arr[i], b2 = arr[ixj];
                    bool up = ((i & k) == 0);
                    if ((a > b2) == up) { arr[i] = b2; arr[ixj] = a; }
                }
            }
            __syncthreads();
        }
    }
    if (tid < MAXDET) {
        unsigned long long kk = arr[tid];
        unsigned int hb = (unsigned int)(kk >> 32);
        unsigned int idx = (unsigned int)(kk & 0xFFFFFFFFu);
        float val = __uint_as_float(~hb);      // zeros decode to 0.0f
        float4 b4 = reinterpret_cast<const float4*>(nms_boxes)[(size_t)b * NCAND + idx];
        reinterpret_cast<float4*>(out)[(size_t)b * MAXDET + tid] = b4;          // boxes [B,100,4]
        out[BB * MAXDET * 4 + b * MAXDET + tid] = val;                           // scores [B,100]
        out[BB * MAXDET * 5 + b * MAXDET + tid] = (float)(idx / KTOP + 1);       // labels [B,100]
    }
}

extern "C" void kernel_launch(void* const* d_in, const int* in_sizes, int n_in,
                              void* d_out, int out_size, void* d_ws, size_t ws_size,
                              hipStream_t stream) {
    const float* loc    = (const float*)d_in[0];
    const float* conf   = (const float*)d_in[1];
    const float* priors = (const float*)d_in[2];
    float* out = (float*)d_out;

    // workspace layout (all 16B-aligned)
    char* ws = (char*)d_ws;
    float* boxes      = (float*)ws;                                   // B*N*4 floats
    float* nms_scores = boxes + (size_t)BB * NN * 4;                  // B*8000 floats
    float* nms_boxes  = nms_scores + (size_t)BB * CM1 * KTOP;         // B*8000*4 floats
    float* scoresT    = nms_boxes + (size_t)BB * CM1 * KTOP * 4;      // G*80*N floats

    size_t fixed_bytes = ((size_t)BB * NN * 4 + (size_t)BB * CM1 * KTOP * 5) * sizeof(float);
    size_t per_img     = (size_t)CM1 * NN * sizeof(float);
    int G = 1;
    if (ws_size > fixed_bytes) {
        size_t g = (ws_size - fixed_bytes) / per_img;
        G = (g < 1) ? 1 : (g > BB ? BB : (int)g);
    }

    decode_kernel<<<(BB * NN + 255) / 256, 256, 0, stream>>>(loc, priors, boxes);

    const int tiles = (NN + 127) / 128;
    for (int b0 = 0; b0 < BB; b0 += G) {
        int g = (BB - b0 < G) ? (BB - b0) : G;
        softmax_tr_kernel<<<g * tiles, 128, 0, stream>>>(conf, scoresT, b0);
        topk_nms_kernel<<<g * CM1, 256, 0, stream>>>(scoresT, boxes, nms_scores, nms_boxes, b0);
    }

    final_topk_kernel<<<BB, 256, 0, stream>>>(nms_scores, nms_boxes, out);
}